// Round 10
// baseline (131.031 us; speedup 1.0000x reference)
//
#include <hip/hip_runtime.h>
#include <hip/hip_bf16.h>
#include <stdint.h>

// Problem constants (from reference)
#define D_DIM  100
#define DISTW  10
#define E_NUM  1890     // number of band pairs
#define HID    64
#define NSIG   52       // cols 0..51 sigmoid features; 52..63 cos features
#define NPF    12
#define N_ROWS 2048
#define ITERS  (N_ROWS / 64)          // 32 (merged: one block per e)
#define TOLV   1e-4f
#define MAT    (D_DIM * D_DIM)        // 10000
#define TOT_ELEMS (N_ROWS * MAT)      // 20,480,000 (multiple of 4)
#define FB     158                    // fill blocks: 1890 + 158 = 2048 = 8*256
#define ZPER   129624                 // ceil(TOT/FB) rounded to x4; guard at TOT

// Feature LUTs: 1024-entry nearest-neighbor, values pre-rounded to bf16
#define TS        1024
#define F_SCALE   (TS / 13.0f)             // feature z in [-6.5, 6.5]
#define F_OFF     (TS * 0.5f + 0.5f)       // +0.5 -> trunc == round-nearest
#define NEGLOG2E  (-1.44269504f)

typedef __attribute__((ext_vector_type(8))) short bf16x8;
typedef __attribute__((ext_vector_type(4))) float f32x4;
typedef __attribute__((ext_vector_type(2))) float f32x2;

__device__ __forceinline__ float fast_exp2(float x) { return __builtin_amdgcn_exp2f(x); }
__device__ __forceinline__ float fast_rcp(float x)  { return __builtin_amdgcn_rcpf(x); }
__device__ __forceinline__ float fast_cosr(float x) { return __builtin_amdgcn_cosf(x); } // cos(2*pi*x)

__device__ __forceinline__ float sigmoid_exact(float x) {
    return fast_rcp(1.0f + fast_exp2(x * NEGLOG2E));
}

__device__ __forceinline__ short f2bf(float x) {
    __hip_bfloat16 h = __float2bfloat16(x);
    return __builtin_bit_cast(short, h);
}

// value -> f32 with mantissa pre-rounded to bf16 and low 16 bits zeroed,
// so a later v_perm extraction of the high half IS the RTNE bf16.
__device__ __forceinline__ float prebf(float x) {
    uint32_t u = ((uint32_t)(uint16_t)f2bf(x)) << 16;
    return __builtin_bit_cast(float, u);
}

// 16-lane-group sum via DPP row_shr (pure VALU). row_shr:N moves lane i-N -> i
// (bound_ctrl zero-fills), so the full group sum lands in lane 15 of each group.
__device__ __forceinline__ float dpp_sum16(float v) {
    int x;
    x = __builtin_amdgcn_update_dpp(0, __builtin_bit_cast(int, v), 0x118, 0xF, 0xF, true);
    v += __builtin_bit_cast(float, x);
    x = __builtin_amdgcn_update_dpp(0, __builtin_bit_cast(int, v), 0x114, 0xF, 0xF, true);
    v += __builtin_bit_cast(float, x);
    x = __builtin_amdgcn_update_dpp(0, __builtin_bit_cast(int, v), 0x112, 0xF, 0xF, true);
    v += __builtin_bit_cast(float, x);
    x = __builtin_amdgcn_update_dpp(0, __builtin_bit_cast(int, v), 0x111, 0xF, 0xF, true);
    v += __builtin_bit_cast(float, x);
    return v;   // valid in lane 15 of each 16-lane group
}

union ABfrag { bf16x8 v; uint32_t u[4]; };

// features for one t (r8-proven path): pk_fma index pair -> cvt -> lshl_add
// -> 2 LDS gathers -> 1 v_perm pack (tables hold bf16-pre-rounded floats)
#define FEAT_PAIR(AF, K, TV) {                                              \
    f32x2 x2 = (f32x2){(TV), (TV)} * cw[K] + cb[K];                         \
    uint32_t b0 = ((uint32_t)x2.x) << 2;                                    \
    uint32_t b1 = ((uint32_t)x2.y) << 2;                                    \
    uint32_t g0 = *(const uint32_t*)(lutB + b0);                            \
    uint32_t g1 = *(const uint32_t*)(lutB + b1);                            \
    AF[(K) >> 2].u[(K) & 3] = __builtin_amdgcn_perm(g1, g0, 0x07060302); }
#define FEAT16(AF, TV) { FEAT_PAIR(AF,0,TV) FEAT_PAIR(AF,1,TV)              \
    FEAT_PAIR(AF,2,TV) FEAT_PAIR(AF,3,TV) FEAT_PAIR(AF,4,TV)                \
    FEAT_PAIR(AF,5,TV) FEAT_PAIR(AF,6,TV) FEAT_PAIR(AF,7,TV) }

__global__ __launch_bounds__(256, 4)
void golem_kernel(const float* __restrict__ T,   const float* __restrict__ W1,
                  const float* __restrict__ b1,  const float* __restrict__ W1p,
                  const float* __restrict__ b1p, const float* __restrict__ W2,
                  const float* __restrict__ b2,  const float* __restrict__ W3,
                  const float* __restrict__ b3,  const float* __restrict__ beta,
                  const float* __restrict__ bias_p, float* __restrict__ Bout)
{
    const int tid = threadIdx.x;

    // ---------------- zero-fill blocks (disjoint cells from band writers) ---
    if (blockIdx.x >= E_NUM) {
        const int zb = (int)blockIdx.x - E_NUM;       // 0..FB-1
        const size_t base = (size_t)zb * ZPER;
        for (int off = tid * 4; off < ZPER; off += 256 * 4) {
            const size_t i = base + off;
            if (i >= TOT_ELEMS) break;
            const int cell = (int)(i % MAT);
            const int r = cell / D_DIM;
            const int c = cell - r * D_DIM;
            const bool fast = (c <= D_DIM - 4) && ((c + 3 < r - DISTW) || (c > r + DISTW));
            if (fast) {
                *reinterpret_cast<f32x4*>(Bout + i) = (f32x4){0.0f, 0.0f, 0.0f, 0.0f};
            } else {
                #pragma unroll
                for (int k = 0; k < 4; ++k) {
                    const size_t j = i + k;
                    const int cell2 = (int)(j % MAT);
                    const int r2 = cell2 / D_DIM;
                    const int c2 = cell2 - r2 * D_DIM;
                    const int d = c2 - r2;
                    const bool band = (d >= -DISTW) && (d <= DISTW) && (d != 0);
                    if (!band) Bout[j] = 0.0f;
                }
            }
        }
        return;
    }

    // ---------------- main band blocks (one per e, all 2048 rows) ----------
    const int e    = blockIdx.x;
    const int lane = tid & 63;
    const int wave = tid >> 6;   // 0..3
    const int g    = lane >> 4;  // 0..3 (k-group)
    const int lm   = lane & 15;

    // sLut: [0,TS) = sigma(sigma(z)); [TS,2TS) = sigma(cos(..z..)); bf16-pre-rounded
    __shared__ float sLut[2 * TS];
    __shared__ float sWA[HID], sWB[HID], sW3[HID], sB2[HID];
    __shared__ float sScal[1];   // b3
    __shared__ int   sRC;

    {
        const float cc1 = beta[e] * 0.05f;            // rad->rev
        const float cc2 = bias_p[e] * 0.15915494309f;
        for (int i = tid; i < TS; i += 256) {
            float x  = (i - (TS / 2)) * (13.0f / TS);
            sLut[i]      = prebf(sigmoid_exact(sigmoid_exact(x)));
            sLut[TS + i] = prebf(sigmoid_exact(fast_cosr(fmaf(x, cc1, cc2))));
        }
    }

    if (tid < HID) {
        float wa, wb;
        if (tid < NSIG) { wa = W1 [e * NSIG + tid];         wb = b1 [e * NSIG + tid]; }
        else            { wa = W1p[e * NPF + (tid - NSIG)]; wb = b1p[e * NPF + (tid - NSIG)]; }
        sWA[tid] = wa; sWB[tid] = wb;
        sW3[tid] = W3[e * HID + tid];
        sB2[tid] = b2[e * HID + tid];
    }
    if (tid == 0) {
        sScal[0] = b3[e];
        int r = 0, off = 0;
        for (;;) {
            int lo = r - DISTW; if (lo < 0) lo = 0;
            int hi = r + DISTW; if (hi > D_DIM - 1) hi = D_DIM - 1;
            int cnt = hi - lo;
            if (e < off + cnt) {
                int idx = e - off;
                int c = lo + idx;
                if (c >= r) c += 1;
                sRC = r * D_DIM + c;
                break;
            }
            off += cnt; ++r;
        }
    }
    __syncthreads();

    // W2[e] as bf16 B-fragments in registers, PRE-SCALED by -log2(e) so the
    // MFMA accumulator directly feeds sigma(pre) = rcp(1 + exp2(acc)).
    const float* W2e = W2 + (size_t)e * (HID * HID);
    bf16x8 bfrag[2][4];
    #pragma unroll
    for (int kk = 0; kk < 2; ++kk)
        #pragma unroll
        for (int ct = 0; ct < 4; ++ct)
            #pragma unroll
            for (int j = 0; j < 8; ++j)
                bfrag[kk][ct][j] = f2bf(W2e[(8 * g + j + 32 * kk) * HID + 16 * ct + lm] * NEGLOG2E);

    // per-lane feature params as f32x2 pairs (pk_fma); cos-table base (1024)
    // folded into cb (exact in f32, floor distributes over +1024)
    f32x2 cw[8], cb[8];
    #pragma unroll
    for (int k = 0; k < 8; ++k) {
        int q = k >> 2, j0 = 2 * (k & 3);
        int c0 = 8 * g + j0 + 32 * q;
        float base0 = F_OFF + ((c0     < NSIG) ? 0.0f : (float)TS);
        float base1 = F_OFF + ((c0 + 1 < NSIG) ? 0.0f : (float)TS);
        cw[k] = (f32x2){sWA[c0] * F_SCALE, sWA[c0 + 1] * F_SCALE};
        cb[k] = (f32x2){fmaf(sWB[c0], F_SCALE, base0), fmaf(sWB[c0 + 1], F_SCALE, base1)};
    }

    float b2v[4], w3v[4];
    #pragma unroll
    for (int ct = 0; ct < 4; ++ct) {
        b2v[ct] = sB2[16 * ct + lm] * NEGLOG2E;   // pre-scaled like W2
        w3v[ct] = sW3[16 * ct + lm];
    }
    const float bias3 = sScal[0];
    const int   rcoff = sRC;
    const char* lutB  = (const char*)sLut;
    // T read directly from global (16 distinct addresses per wave, 4-way
    // broadcast; 8 KB total -> L1-resident)
    const float* Tg = T + wave * 16 + lm;

    for (int it = 0; it < ITERS; ++it) {
        const float t = Tg[it * 64];

        ABfrag af[2];
        FEAT16(af, t);

        // C-init = pre-scaled b2
        f32x4 acc[4];
        #pragma unroll
        for (int ct = 0; ct < 4; ++ct)
            acc[ct] = (f32x4){b2v[ct], b2v[ct], b2v[ct], b2v[ct]};
        #pragma unroll
        for (int ct = 0; ct < 4; ++ct) {
            acc[ct] = __builtin_amdgcn_mfma_f32_16x16x32_bf16(af[0].v, bfrag[0][ct], acc[ct], 0, 0, 0);
            acc[ct] = __builtin_amdgcn_mfma_f32_16x16x32_bf16(af[1].v, bfrag[1][ct], acc[ct], 0, 0, 0);
        }

        // epilogue on trans pipe: sigma(pre) = rcp(1 + exp2(acc)) (acc pre-scaled)
        float p[4];
        #pragma unroll
        for (int reg = 0; reg < 4; ++reg) {
            float s = 0.0f;
            #pragma unroll
            for (int ct = 0; ct < 4; ++ct)
                s = fmaf(fast_rcp(1.0f + fast_exp2(acc[ct][reg])), w3v[ct], s);
            p[reg] = dpp_sum16(s);
        }

        // full group sum lives in lane 15 of each 16-lane group
        if (lm == 15) {
            #pragma unroll
            for (int r = 0; r < 4; ++r) {
                float out = p[r] + bias3;
                if (fabsf(out) < TOLV) out = 0.0f;
                int row = it * 64 + wave * 16 + 4 * g + r;
                Bout[(size_t)row * MAT + rcoff] = out;
            }
        }
    }
}

extern "C" void kernel_launch(void* const* d_in, const int* in_sizes, int n_in,
                              void* d_out, int out_size, void* d_ws, size_t ws_size,
                              hipStream_t stream) {
    const float* T      = (const float*)d_in[0];
    const float* W1     = (const float*)d_in[1];
    const float* b1     = (const float*)d_in[2];
    const float* W1p    = (const float*)d_in[3];
    const float* b1p    = (const float*)d_in[4];
    const float* W2     = (const float*)d_in[5];
    const float* b2     = (const float*)d_in[6];
    const float* W3     = (const float*)d_in[7];
    const float* b3     = (const float*)d_in[8];
    const float* beta   = (const float*)d_in[9];
    const float* bias_p = (const float*)d_in[10];
    float* Bout = (float*)d_out;

    // 1890 band blocks + 158 fill blocks = 2048 = exactly 8 per CU
    golem_kernel<<<dim3(E_NUM + FB), dim3(256), 0, stream>>>(
        T, W1, b1, W1p, b1p, W2, b2, W3, b3, beta, bias_p, Bout);
}

// Round 11
// 114.281 us; speedup vs baseline: 1.1466x; 1.1466x over previous
//
#include <hip/hip_runtime.h>
#include <hip/hip_bf16.h>
#include <stdint.h>

// Problem constants (from reference)
#define D_DIM  100
#define DISTW  10
#define E_NUM  1890     // number of band pairs
#define HID    64
#define NSIG   52       // cols 0..51 sigmoid features; 52..63 cos features
#define NPF    12
#define N_ROWS 2048
#define NHALF  1024     // rows per block (grid.y = 2)
#define ITERS  (NHALF / 64)           // 16
#define TOLV   1e-4f
#define MAT    (D_DIM * D_DIM)        // 10000
#define HALF_ELEMS (NHALF * MAT)      // 10,240,000
#define ZB     256                    // zero-fill blocks per half

// LUTs: 1024-entry nearest-neighbor, values pre-rounded to bf16
// [0,TS): sigma(sigma(z)); [TS,2TS): sigma(cos(..z..)); [2TS,3TS): sigma(x)
#define TS        1024
#define F_SCALE   (TS / 13.0f)             // feature z in [-6.5, 6.5]
#define F_OFF     (TS * 0.5f + 0.5f)       // +0.5 -> trunc == round-nearest
#define E_SCALE   (TS / 16.0f)             // epilogue pre-act in [-8, 8]
// element-domain constant incl sigma-table base (2*TS); |pre-act| < 6 => no clamp
#define E_CONST   (TS * 0.5f + 0.5f + 2.0f * TS)   // 2560.5

typedef __attribute__((ext_vector_type(8))) short bf16x8;
typedef __attribute__((ext_vector_type(4))) float f32x4;
typedef __attribute__((ext_vector_type(2))) float f32x2;

__device__ __forceinline__ float fast_exp2(float x) { return __builtin_amdgcn_exp2f(x); }
__device__ __forceinline__ float fast_rcp(float x)  { return __builtin_amdgcn_rcpf(x); }
__device__ __forceinline__ float fast_cosr(float x) { return __builtin_amdgcn_cosf(x); } // cos(2*pi*x)

__device__ __forceinline__ float sigmoid_exact(float x) {
    return fast_rcp(1.0f + fast_exp2(x * -1.44269504f));
}

__device__ __forceinline__ short f2bf(float x) {
    __hip_bfloat16 h = __float2bfloat16(x);
    return __builtin_bit_cast(short, h);
}

// value -> f32 with mantissa pre-rounded to bf16 and low 16 bits zeroed,
// so a later v_perm extraction of the high half IS the RTNE bf16.
__device__ __forceinline__ float prebf(float x) {
    uint32_t u = ((uint32_t)(uint16_t)f2bf(x)) << 16;
    return __builtin_bit_cast(float, u);
}

// 16-lane-group sum via DPP row_shr (pure VALU). row_shr:N moves lane i-N -> i
// (bound_ctrl zero-fills), so the full group sum lands in lane 15 of each group.
__device__ __forceinline__ float dpp_sum16(float v) {
    int x;
    x = __builtin_amdgcn_update_dpp(0, __builtin_bit_cast(int, v), 0x118, 0xF, 0xF, true);
    v += __builtin_bit_cast(float, x);
    x = __builtin_amdgcn_update_dpp(0, __builtin_bit_cast(int, v), 0x114, 0xF, 0xF, true);
    v += __builtin_bit_cast(float, x);
    x = __builtin_amdgcn_update_dpp(0, __builtin_bit_cast(int, v), 0x112, 0xF, 0xF, true);
    v += __builtin_bit_cast(float, x);
    x = __builtin_amdgcn_update_dpp(0, __builtin_bit_cast(int, v), 0x111, 0xF, 0xF, true);
    v += __builtin_bit_cast(float, x);
    return v;   // valid in lane 15 of each 16-lane group
}

union ABfrag { bf16x8 v; uint32_t u[4]; };

// features for one t: pk_fma index pair -> cvt -> lshl -> 2 LDS gathers
// -> 1 v_perm pack (tables hold bf16-pre-rounded floats)
#define FEAT_PAIR(AF, K, TV) {                                              \
    f32x2 x2 = (f32x2){(TV), (TV)} * cw[K] + cb[K];                         \
    uint32_t b0 = ((uint32_t)x2.x) << 2;                                    \
    uint32_t b1 = ((uint32_t)x2.y) << 2;                                    \
    uint32_t g0 = *(const uint32_t*)(lutB + b0);                            \
    uint32_t g1 = *(const uint32_t*)(lutB + b1);                            \
    AF[(K) >> 2].u[(K) & 3] = __builtin_amdgcn_perm(g1, g0, 0x07060302); }
#define FEAT16(AF, TV) { FEAT_PAIR(AF,0,TV) FEAT_PAIR(AF,1,TV)              \
    FEAT_PAIR(AF,2,TV) FEAT_PAIR(AF,3,TV) FEAT_PAIR(AF,4,TV)                \
    FEAT_PAIR(AF,5,TV) FEAT_PAIR(AF,6,TV) FEAT_PAIR(AF,7,TV) }

__global__ __launch_bounds__(256, 4)
void golem_kernel(const float* __restrict__ T,   const float* __restrict__ W1,
                  const float* __restrict__ b1,  const float* __restrict__ W1p,
                  const float* __restrict__ b1p, const float* __restrict__ W2,
                  const float* __restrict__ b2,  const float* __restrict__ W3,
                  const float* __restrict__ b3,  const float* __restrict__ beta,
                  const float* __restrict__ bias_p, float* __restrict__ Bout)
{
    const int tid  = threadIdx.x;
    const int half = blockIdx.y;

    // ---------------- zero-fill blocks (disjoint cells from band writers) ---
    if (blockIdx.x >= E_NUM) {
        const int zb  = (int)blockIdx.x - E_NUM;      // 0..ZB-1
        const int per = HALF_ELEMS / ZB;              // 40000 (multiple of 4)
        const size_t base = (size_t)half * HALF_ELEMS + (size_t)zb * per;
        for (int off = tid * 4; off < per; off += 256 * 4) {
            const size_t i = base + off;
            const int cell = (int)(i % MAT);
            const int r = cell / D_DIM;
            const int c = cell - r * D_DIM;
            const bool fast = (c <= D_DIM - 4) && ((c + 3 < r - DISTW) || (c > r + DISTW));
            if (fast) {
                *reinterpret_cast<f32x4*>(Bout + i) = (f32x4){0.0f, 0.0f, 0.0f, 0.0f};
            } else {
                #pragma unroll
                for (int k = 0; k < 4; ++k) {
                    const size_t j = i + k;
                    const int cell2 = (int)(j % MAT);
                    const int r2 = cell2 / D_DIM;
                    const int c2 = cell2 - r2 * D_DIM;
                    const int d = c2 - r2;
                    const bool band = (d >= -DISTW) && (d <= DISTW) && (d != 0);
                    if (!band) Bout[j] = 0.0f;
                }
            }
        }
        return;
    }

    // ---------------- main band blocks -------------------------------------
    const int e    = blockIdx.x;
    const int lane = tid & 63;
    const int wave = tid >> 6;   // 0..3
    const int g    = lane >> 4;  // 0..3 (k-group)
    const int lm   = lane & 15;

    __shared__ float sLut[3 * TS];
    __shared__ float sWA[HID], sWB[HID], sW3[HID], sB2[HID];
    __shared__ float sScal[1];   // b3
    __shared__ int   sRC;

    {
        const float cc1 = beta[e] * 0.05f;            // rad->rev
        const float cc2 = bias_p[e] * 0.15915494309f;
        for (int i = tid; i < TS; i += 256) {
            float x  = (i - (TS / 2)) * (13.0f / TS);
            sLut[i]          = prebf(sigmoid_exact(sigmoid_exact(x)));
            sLut[TS + i]     = prebf(sigmoid_exact(fast_cosr(fmaf(x, cc1, cc2))));
            float xe = (i - (TS / 2)) * (16.0f / TS);
            sLut[2 * TS + i] = sigmoid_exact(xe);     // epilogue sigma (f32 values)
        }
    }

    if (tid < HID) {
        float wa, wb;
        if (tid < NSIG) { wa = W1 [e * NSIG + tid];         wb = b1 [e * NSIG + tid]; }
        else            { wa = W1p[e * NPF + (tid - NSIG)]; wb = b1p[e * NPF + (tid - NSIG)]; }
        sWA[tid] = wa; sWB[tid] = wb;
        sW3[tid] = W3[e * HID + tid];
        sB2[tid] = b2[e * HID + tid];
    }
    if (tid == 0) {
        sScal[0] = b3[e];
        int r = 0, off = 0;
        for (;;) {
            int lo = r - DISTW; if (lo < 0) lo = 0;
            int hi = r + DISTW; if (hi > D_DIM - 1) hi = D_DIM - 1;
            int cnt = hi - lo;
            if (e < off + cnt) {
                int idx = e - off;
                int c = lo + idx;
                if (c >= r) c += 1;
                sRC = r * D_DIM + c;
                break;
            }
            off += cnt; ++r;
        }
    }
    __syncthreads();

    // W2[e] as bf16 B-fragments in registers (plain, no pre-scale: LUT epilogue)
    const float* W2e = W2 + (size_t)e * (HID * HID);
    bf16x8 bfrag[2][4];
    #pragma unroll
    for (int kk = 0; kk < 2; ++kk)
        #pragma unroll
        for (int ct = 0; ct < 4; ++ct)
            #pragma unroll
            for (int j = 0; j < 8; ++j)
                bfrag[kk][ct][j] = f2bf(W2e[(8 * g + j + 32 * kk) * HID + 16 * ct + lm]);

    // per-lane feature params as f32x2 pairs (pk_fma); cos-table base (1024)
    // folded into cb (exact in f32, floor distributes over +1024)
    f32x2 cw[8], cb[8];
    #pragma unroll
    for (int k = 0; k < 8; ++k) {
        int q = k >> 2, j0 = 2 * (k & 3);
        int c0 = 8 * g + j0 + 32 * q;
        float base0 = F_OFF + ((c0     < NSIG) ? 0.0f : (float)TS);
        float base1 = F_OFF + ((c0 + 1 < NSIG) ? 0.0f : (float)TS);
        cw[k] = (f32x2){sWA[c0] * F_SCALE, sWA[c0 + 1] * F_SCALE};
        cb[k] = (f32x2){fmaf(sWB[c0], F_SCALE, base0), fmaf(sWB[c0 + 1], F_SCALE, base1)};
    }

    float b2v[4], w3v[4];
    #pragma unroll
    for (int ct = 0; ct < 4; ++ct) {
        b2v[ct] = sB2[16 * ct + lm];
        w3v[ct] = sW3[16 * ct + lm];
    }
    const float bias3 = sScal[0];
    const int   rcoff = sRC;
    const char* lutB  = (const char*)sLut;
    // T read directly from global (16 distinct addresses per wave, 4-way
    // broadcast; 8 KB total -> L1-resident)
    const float* Tg = T + half * NHALF + wave * 16 + lm;

    for (int it = 0; it < ITERS; ++it) {
        const float t = Tg[it * 64];

        ABfrag af[2];
        FEAT16(af, t);

        // C-init = b2 (col = lm fixed per lane -> same value across regs)
        f32x4 acc[4];
        #pragma unroll
        for (int ct = 0; ct < 4; ++ct)
            acc[ct] = (f32x4){b2v[ct], b2v[ct], b2v[ct], b2v[ct]};
        #pragma unroll
        for (int ct = 0; ct < 4; ++ct) {
            acc[ct] = __builtin_amdgcn_mfma_f32_16x16x32_bf16(af[0].v, bfrag[0][ct], acc[ct], 0, 0, 0);
            acc[ct] = __builtin_amdgcn_mfma_f32_16x16x32_bf16(af[1].v, bfrag[1][ct], acc[ct], 0, 0, 0);
        }

        // epilogue via sigma-LUT (LDS pipe): index = acc*E_SCALE + E_CONST
        // (pk math); |pre-act| < 6 -> indices inside table, no clamp
        f32x4 ix[4];
        #pragma unroll
        for (int ct = 0; ct < 4; ++ct)
            ix[ct] = acc[ct] * (f32x4){E_SCALE, E_SCALE, E_SCALE, E_SCALE}
                   + (f32x4){E_CONST, E_CONST, E_CONST, E_CONST};
        float p[4];
        #pragma unroll
        for (int reg = 0; reg < 4; ++reg) {
            float s = 0.0f;
            #pragma unroll
            for (int ct = 0; ct < 4; ++ct) {
                uint32_t bi = ((uint32_t)ix[ct][reg]) << 2;
                s = fmaf(*(const float*)(lutB + bi), w3v[ct], s);
            }
            p[reg] = dpp_sum16(s);
        }

        // full group sum lives in lane 15 of each 16-lane group
        if (lm == 15) {
            #pragma unroll
            for (int r = 0; r < 4; ++r) {
                float out = p[r] + bias3;
                if (fabsf(out) < TOLV) out = 0.0f;
                int row = half * NHALF + it * 64 + wave * 16 + 4 * g + r;
                Bout[(size_t)row * MAT + rcoff] = out;
            }
        }
    }
}

extern "C" void kernel_launch(void* const* d_in, const int* in_sizes, int n_in,
                              void* d_out, int out_size, void* d_ws, size_t ws_size,
                              hipStream_t stream) {
    const float* T      = (const float*)d_in[0];
    const float* W1     = (const float*)d_in[1];
    const float* b1     = (const float*)d_in[2];
    const float* W1p    = (const float*)d_in[3];
    const float* b1p    = (const float*)d_in[4];
    const float* W2     = (const float*)d_in[5];
    const float* b2     = (const float*)d_in[6];
    const float* W3     = (const float*)d_in[7];
    const float* b3     = (const float*)d_in[8];
    const float* beta   = (const float*)d_in[9];
    const float* bias_p = (const float*)d_in[10];
    float* Bout = (float*)d_out;

    // zero-fill is fused into the kernel grid (blocks >= E_NUM), overlapping compute
    golem_kernel<<<dim3(E_NUM + ZB, 2), dim3(256), 0, stream>>>(
        T, W1, b1, W1p, b1p, W2, b2, W3, b3, beta, bias_p, Bout);
}